// Round 6
// baseline (4678.553 us; speedup 1.0000x reference)
//
#include <hip/hip_runtime.h>

typedef unsigned short u16;
typedef __attribute__((ext_vector_type(4))) float f32x4;
typedef __attribute__((ext_vector_type(8))) __bf16 bf16x8;
typedef __attribute__((ext_vector_type(8))) u16 u16x8;
typedef __attribute__((ext_vector_type(4))) unsigned int u32x4;

#define ALPHA_F 0.1f
#define G1BLK 128
#define NBLK 224

// Cl(3,0): e_a * e_c = (-1)^p e_{a^c}  [validated R1-R4]
__device__ __host__ constexpr bool SGN(int a, int c) {
  return ((((c & 1) & (((a >> 1) ^ (a >> 2)) & 1)) ^
           (((c >> 1) & 1) & ((a >> 2) & 1))) != 0);
}
__device__ __host__ constexpr float REVF(int c) {
  const int r = (c & 1) + ((c >> 1) & 1) + ((c >> 2) & 1);
  return (r >= 2) ? -1.f : 1.f;
}
__device__ __forceinline__ u16 bf_rnd(float f) {
  unsigned u = __float_as_uint(f);
  return (u16)((u + 0x7FFFu + ((u >> 16) & 1u)) >> 16);
}
__device__ __forceinline__ float bf_val(u16 h) {
  return __uint_as_float(((unsigned)h) << 16);
}
__device__ __forceinline__ f32x4 mf(bf16x8 a, bf16x8 b, f32x4 c) {
  return __builtin_amdgcn_mfma_f32_16x16x32_bf16(a, b, c, 0, 0, 0);
}
__device__ __forceinline__ bf16x8 negf(bf16x8 v) {
  u16x8 u = __builtin_bit_cast(u16x8, v);
  const u16x8 m = {0x8000, 0x8000, 0x8000, 0x8000, 0x8000, 0x8000, 0x8000, 0x8000};
  u = u ^ m;
  return __builtin_bit_cast(bf16x8, u);
}

// ===========================================================================
// Compose pgemm (R4-validated core): blade-plane GEMM, 3-pass split bf16,
// K-split + counter-gated deterministic reduce.
// ===========================================================================
struct CRole {
  const u16 *Ahi, *Alo;
  const u16* Vpk;
  float* P;
  int* ctr;
  u16 *Zhi, *Zlo;
  float* outRaw;
  float* outZf;
  int AR, AN, acol0, npan, ksl, NC, ctrb;
};

__global__ __launch_bounds__(256) void pgemm(CRole r0, CRole r1, CRole r2,
                                             int n0, int n01) {
  __shared__ u16 Vs[2][16384];
  __shared__ int islast;

  CRole R;
  int r;
  const int bid = blockIdx.x;
  if (bid < n0) { R = r0; r = bid; }
  else if (bid < n01) { R = r1; r = bid - n0; }
  else { R = r2; r = bid - n01; }

  const int tid = threadIdx.x;
  const int w = tid >> 6, l = tid & 63;
  const int lg = l >> 4, lm = l & 15;

  const int sl = r % R.ksl;
  const int slot = r / R.ksl;
  const int p = slot % R.npan;
  const int rb = slot / R.npan;
  const int rowg = rb * 64 + w * 16 + lm;
  const int nchtot = R.ksl * 4;

  f32x4 acc[8];
#pragma unroll
  for (int i = 0; i < 8; ++i) acc[i] = f32x4{0.f, 0.f, 0.f, 0.f};

  auto VSTAGE = [&](int db, int ch) {
    const u16* src = R.Vpk + ((size_t)p * nchtot + sl * 4 + ch) * 8192;
#pragma unroll
    for (int i = 0; i < 4; ++i) {
      const int g = tid * 4 + i;
      const u32x4 v = *(const u32x4*)(src + (size_t)g * 8);
      u16* d = &Vs[db][(g >> 9) * 8192 + ((g >> 6) & 7) * 1024 +
                       ((g >> 4) & 3) * 128 + (g & 15) * 8];
      *(u32x4*)d = v;
      *(u32x4*)(d + 512) = v ^ 0x80008000u;
    }
  };
  auto ALOAD = [&](bf16x8* h, bf16x8* lo2, int ch) {
    const int coff = R.acol0 + (sl * 4 + ch) * 32 + lg * 8;
#pragma unroll
    for (int a = 0; a < 8; ++a) {
      const size_t o = ((size_t)(a * R.AR + rowg)) * R.AN + coff;
      h[a] = *(const bf16x8*)(R.Ahi + o);
      lo2[a] = *(const bf16x8*)(R.Alo + o);
    }
  };
  auto COMPUTE = [&](int db, const bf16x8* h, const bf16x8* lo2) {
    const int fb = lg * 128 + lm * 8;
#pragma unroll
    for (int c = 0; c < 8; ++c) {
      const bf16x8 vhp = *(const bf16x8*)&Vs[db][fb + c * 1024];
      const bf16x8 vhn = *(const bf16x8*)&Vs[db][fb + c * 1024 + 512];
      const bf16x8 vlp = *(const bf16x8*)&Vs[db][fb + 8192 + c * 1024];
      const bf16x8 vln = *(const bf16x8*)&Vs[db][fb + 8192 + c * 1024 + 512];
#pragma unroll
      for (int a = 0; a < 8; ++a) {
        const int k = a ^ c;
        const bf16x8 vh = SGN(a, c) ? vhn : vhp;
        const bf16x8 vl = SGN(a, c) ? vln : vlp;
        acc[k] = mf(h[a], vh, acc[k]);
        acc[k] = mf(lo2[a], vh, acc[k]);
        acc[k] = mf(h[a], vl, acc[k]);
      }
    }
  };

  bf16x8 Ah[8], Al8[8], Bh[8], Bl[8];
  VSTAGE(0, 0); ALOAD(Ah, Al8, 0);
  __syncthreads();
  VSTAGE(1, 1); ALOAD(Bh, Bl, 1);
  COMPUTE(0, Ah, Al8);
  __syncthreads();
  VSTAGE(0, 2); ALOAD(Ah, Al8, 2);
  COMPUTE(1, Bh, Bl);
  __syncthreads();
  VSTAGE(1, 3); ALOAD(Bh, Bl, 3);
  COMPUTE(0, Ah, Al8);
  __syncthreads();
  COMPUTE(1, Bh, Bl);

  float* Ps = R.P + ((size_t)slot * R.ksl + sl) * 8192;
#pragma unroll
  for (int k = 0; k < 8; ++k)
    *(f32x4*)&Ps[(size_t)((w * 8 + k) * 64 + l) * 4] = acc[k];

  __threadfence();
  __syncthreads();
  if (tid == 0) {
    int* cp = &R.ctr[R.ctrb + slot];
    const int c = atomicAdd(cp, 1);
    const int last = (c == R.ksl - 1);
    if (last) *cp = 0;
    islast = last;
  }
  __syncthreads();
  if (!islast) return;
  __threadfence();

  const int idx0 = tid * 8;
  f32x4 s4[8];
#pragma unroll
  for (int u = 0; u < 8; ++u) s4[u] = f32x4{0.f, 0.f, 0.f, 0.f};
  const float* Pb = R.P + (size_t)slot * R.ksl * 8192;
  for (int ss = 0; ss < R.ksl; ++ss) {
    const float* q = Pb + (size_t)ss * 8192 + (size_t)idx0 * 4;
#pragma unroll
    for (int u = 0; u < 8; ++u) s4[u] += *(const f32x4*)&q[u * 4];
  }

  const int kk = (idx0 >> 6) & 7, bt = idx0 >> 9, ln0 = idx0 & 63;
  const int lg0 = ln0 >> 4, m0 = ln0 & 15;

  if (R.outRaw) {
#pragma unroll
    for (int q2 = 0; q2 < 4; ++q2) {
      const int row = rb * 64 + bt * 16 + lg0 * 4 + q2;
#pragma unroll
      for (int u = 0; u < 8; ++u)
        R.outRaw[((size_t)row * R.NC + p * 16 + m0 + u) * 8 + kk] = s4[u][q2];
    }
  }
  if (R.Zhi) {
    const int cbl = (p * 16 + m0) >> 3;
#pragma unroll
    for (int q2 = 0; q2 < 4; ++q2) {
      const int b = bt * 16 + lg0 * 4 + q2;
      u16x8 h8, l8;
#pragma unroll
      for (int u = 0; u < 8; ++u) {
        const float v = s4[u][q2];
        const u16 hh = bf_rnd(v);
        h8[u] = hh;
        l8[u] = bf_rnd(v - bf_val(hh));
      }
      const size_t zo = (((size_t)kk * 96 + 32 + cbl) * 64 + b) * 8;
      *(u16x8*)&R.Zhi[zo] = h8;
      *(u16x8*)&R.Zlo[zo] = l8;
    }
  }
  if (R.outZf) {
    const int cbl = (p * 16 + m0) >> 3;
#pragma unroll
    for (int q2 = 0; q2 < 4; ++q2) {
      const int b = bt * 16 + lg0 * 4 + q2;
      float* dst = R.outZf + (((size_t)kk * 64 + cbl) * 64 + b) * 8;
      f32x4 v0 = {s4[0][q2], s4[1][q2], s4[2][q2], s4[3][q2]};
      f32x4 v1 = {s4[4][q2], s4[5][q2], s4[6][q2], s4[7][q2]};
      *(f32x4*)dst = v0;
      *(f32x4*)(dst + 4) = v1;
    }
  }
}

// ===========================================================================
// D1: pack raw inputs (R4-validated formulas)
// ===========================================================================
__global__ __launch_bounds__(256) void pack_in(
    const float* __restrict__ x, const float* __restrict__ w1,
    const float* __restrict__ w2, u16* P1h, u16* P1l, u16* Q1, u16* Qc1,
    u16* P2h, u16* P2l, u16* Q2, u16* Axh, u16* Axl, u16* Z0h, u16* Z0l,
    float* out0, int* bar, int* ctr) {
  const int t = blockIdx.x * 256 + threadIdx.x;
  if (t < 131072) {  // w1-space
    const int r = t >> 9, cc = t & 511;
    const float* s = w1 + ((size_t)r * 512 + cc) * 8;
    float v[8];
#pragma unroll
    for (int c = 0; c < 8; ++c) v[c] = s[c];
#pragma unroll
    for (int a = 0; a < 8; ++a) {
      const u16 h = bf_rnd(v[a]);
      P1h[((size_t)a * 512 + cc) * 256 + r] = h;
      P1l[((size_t)a * 512 + cc) * 256 + r] = bf_rnd(v[a] - bf_val(h));
    }
    const size_t ob = (size_t)((cc >> 4) * 8 + (r >> 5)) * 8192 +
                      ((r >> 3) & 3) * 128 + (cc & 15) * 8 + (r & 7);
#pragma unroll
    for (int c = 0; c < 8; ++c) {
      const float q1 = REVF(c) * v[c];
      u16 h = bf_rnd(q1);
      Q1[ob + c * 512] = h;
      Q1[ob + 4096 + c * 512] = bf_rnd(q1 - bf_val(h));
      const float qc = ALPHA_F * q1;
      h = bf_rnd(qc);
      Qc1[ob + c * 512] = h;
      Qc1[ob + 4096 + c * 512] = bf_rnd(qc - bf_val(h));
    }
  } else if (t < 262144) {  // w2-space
    const int u = t - 131072;
    const int r = u >> 8, c2 = u & 255;
    const float* s = w2 + ((size_t)r * 256 + c2) * 8;
    float v[8];
#pragma unroll
    for (int c = 0; c < 8; ++c) v[c] = s[c];
#pragma unroll
    for (int a = 0; a < 8; ++a) {
      const u16 h = bf_rnd(v[a]);
      P2h[((size_t)a * 256 + c2) * 512 + r] = h;
      P2l[((size_t)a * 256 + c2) * 512 + r] = bf_rnd(v[a] - bf_val(h));
    }
    const size_t ob2 = (size_t)((c2 >> 4) * 16 + (r >> 5)) * 8192 +
                       ((r >> 3) & 3) * 128 + (c2 & 15) * 8 + (r & 7);
#pragma unroll
    for (int c = 0; c < 8; ++c) {
      const float q2v = REVF(c) * v[c];
      const u16 h = bf_rnd(q2v);
      Q2[ob2 + c * 512] = h;
      Q2[ob2 + 4096 + c * 512] = bf_rnd(q2v - bf_val(h));
    }
  } else if (t < 278528) {  // x planes
    const int u = t - 262144;
    const int b = u >> 8, n = u & 255;
    const float* s = x + ((size_t)b * 256 + n) * 8;
#pragma unroll
    for (int a = 0; a < 8; ++a) {
      const u16 h = bf_rnd(s[a]);
      Axh[((size_t)a * 64 + b) * 256 + n] = h;
      Axl[((size_t)a * 64 + b) * 256 + n] = bf_rnd(s[a] - bf_val(h));
    }
  } else if (t < 311296) {  // out0 = x
    const int u = t - 278528;
    ((float4*)out0)[u] = ((const float4*)x)[u];
  } else if (t < 344064) {  // Z0 S2-region zero
    const int u = t - 311296;
    const int hl = u >> 14, i = u & 16383;
    const int a = i >> 11, j = i & 2047;
    const u16x8 z = {0, 0, 0, 0, 0, 0, 0, 0};
    u16* Z = hl ? Z0l : Z0h;
    *(u16x8*)&Z[(size_t)a * 49152 + (size_t)j * 8] = z;
  } else if (t < 344424) {
    const int i = t - 344064;
    if (i < 3) bar[i] = 0;
    else if (i < 355) ctr[i - 3] = 0;
  }
}

// ===========================================================================
// D3: pack composed operators into the mainloop V-panel layout (linear LDS img)
//   Vpk[(blk)][ ((c*2+hl)*4 + s)*512 + lg*128 + lm*8 + e ]
// g1: 32p x 4sl x 8c x 4s x 4lg x 16lm = 262144 entries  (FIXED: was 65536)
// g2: 16p x 6sl x (2048)              = 196608 entries  (FIXED: was 98304)
// ===========================================================================
__global__ __launch_bounds__(256) void pack_main(const float* __restrict__ V1raw,
                                                 const float* __restrict__ V2raw,
                                                 const float* __restrict__ w2,
                                                 u16* Vpk1, u16* Vpk2) {
  const int t = blockIdx.x * 256 + threadIdx.x;
  if (t < 262144) {  // g1: (I - a*V1)
    const int lm = t & 15, lg = (t >> 4) & 3, s = (t >> 6) & 3;
    const int c = (t >> 8) & 7, sl = (t >> 11) & 3, p = t >> 13;  // p 0..31
    const int m = p * 16 + lm;
    u16 h8[8], l8[8];
#pragma unroll
    for (int e = 0; e < 8; ++e) {
      const int n = sl * 128 + s * 32 + lg * 8 + e;
      const float val = ((c == 0) && (n == m) ? 1.0f : 0.0f) -
                        ALPHA_F * V1raw[((size_t)n * 512 + m) * 8 + c];
      const u16 hh = bf_rnd(val);
      h8[e] = hh;
      l8[e] = bf_rnd(val - bf_val(hh));
    }
    u16* dst = Vpk1 + ((size_t)(p * 4 + sl) << 15) +
               ((c * 2) * 4 + s) * 512 + lg * 128 + lm * 8;
    *(u16x8*)dst = *(u16x8*)h8;
    *(u16x8*)(dst + 2048) = *(u16x8*)l8;
  } else if (t < 458752) {  // g2: [I - a*V2  |  a*rev(w2)]
    const int j = t - 262144;
    const int p = j / 12288, r2 = j % 12288;  // p 0..15
    const int sl = r2 >> 11, rest = r2 & 2047;
    const int c = (rest >> 8) & 7, s = (rest >> 6) & 3;
    const int lg = (rest >> 4) & 3, lm = rest & 15;
    const int m2 = p * 16 + lm;
    u16 h8[8], l8[8];
#pragma unroll
    for (int e = 0; e < 8; ++e) {
      const int n = sl * 128 + s * 32 + lg * 8 + e;
      float val;
      if (n < 256)
        val = ((c == 0) && (n == m2) ? 1.0f : 0.0f) -
              ALPHA_F * V2raw[((size_t)n * 256 + m2) * 8 + c];
      else
        val = ALPHA_F * REVF(c) * w2[((size_t)(n - 256) * 256 + m2) * 8 + c];
      const u16 hh = bf_rnd(val);
      h8[e] = hh;
      l8[e] = bf_rnd(val - bf_val(hh));
    }
    u16* dst = Vpk2 + ((size_t)(p * 6 + sl) << 15) +
               ((c * 2) * 4 + s) * 512 + lg * 128 + lm * 8;
    *(u16x8*)dst = *(u16x8*)h8;
    *(u16x8*)(dst + 2048) = *(u16x8*)l8;
  }
}

// ===========================================================================
// Persistent main loop. 224 blocks x 512 threads, REGULAR launch (1 blk/CU,
// 224 <= 256 CUs => co-resident; hand-rolled agent-scope barrier).
// ===========================================================================
struct MArgs {
  const u16 *Vpk1, *Vpk2;
  u16 *Z0h, *Z0l, *Z1h, *Z1l;
  const float* c1Z;
  float *Pg1, *Pg2;
  float *out1, *out2;
  int* bar;
};

__device__ __forceinline__ void gbar(int* bar, int idx) {
  __syncthreads();
  __threadfence();
  if (threadIdx.x == 0) {
    int* cnt = &bar[idx & 1];
    if (__hip_atomic_fetch_add(cnt, 1, __ATOMIC_ACQ_REL,
                               __HIP_MEMORY_SCOPE_AGENT) == NBLK - 1) {
      __hip_atomic_store(cnt, 0, __ATOMIC_RELAXED, __HIP_MEMORY_SCOPE_AGENT);
      __hip_atomic_fetch_add(&bar[2], 1, __ATOMIC_RELEASE,
                             __HIP_MEMORY_SCOPE_AGENT);
    } else {
      while (__hip_atomic_load(&bar[2], __ATOMIC_ACQUIRE,
                               __HIP_MEMORY_SCOPE_AGENT) < idx + 1)
        __builtin_amdgcn_s_sleep(2);
    }
  }
  __syncthreads();
  __threadfence();
}

__global__ __launch_bounds__(512, 2) void mainloop(MArgs M) {
  __shared__ u16 lds[49152];  // 64KB V panel + 32KB merge scratch
  float* scratch = (float*)(lds + 32768);

  const int bid = blockIdx.x, tid = threadIdx.x;
  const int w = tid >> 6, l = tid & 63;
  const int lg = l >> 4, lm = l & 15;
  const int rg = w & 3, hf = w >> 2;
  const bool isG1 = bid < G1BLK;
  const int p = isG1 ? (bid >> 2) : (bid - G1BLK) / 6;
  const int sl = isG1 ? (bid & 3) : (bid - G1BLK) % 6;

  // one-time V stage (linear copy; layout pre-baked by pack_main)
  {
    const u16* src = isG1 ? M.Vpk1 + ((size_t)(p * 4 + sl) << 15)
                          : M.Vpk2 + ((size_t)(p * 6 + sl) << 15);
    for (int i = tid; i < 4096; i += 512)
      *(u16x8*)&lds[(size_t)i * 8] = *(const u16x8*)&src[(size_t)i * 8];
  }
  __syncthreads();

  const int fb = lg * 128 + lm * 8;
  const int cbBase = (isG1 ? 32 + sl * 16 : sl * 16) + hf * 8;
  const int rowoff = (rg * 16 + lm) * 8;
  int baridx = 0;

  auto P1 = [&](const u16* Zh, const u16* Zl) {
    f32x4 acc[8];
#pragma unroll
    for (int k = 0; k < 8; ++k) acc[k] = f32x4{0.f, 0.f, 0.f, 0.f};
    bf16x8 A0h[8], A0l[8], A1h[8], A1l[8];
#pragma unroll
    for (int a = 0; a < 8; ++a) {
      const size_t o = (size_t)a * 49152 + (size_t)(cbBase + lg) * 512 + rowoff;
      A0h[a] = *(const bf16x8*)(Zh + o);
      A0l[a] = *(const bf16x8*)(Zl + o);
    }
#pragma unroll
    for (int a = 0; a < 8; ++a) {
      const size_t o =
          (size_t)a * 49152 + (size_t)(cbBase + 4 + lg) * 512 + rowoff;
      A1h[a] = *(const bf16x8*)(Zh + o);
      A1l[a] = *(const bf16x8*)(Zl + o);
    }
#pragma unroll
    for (int st = 0; st < 2; ++st) {
      const int hst = hf * 2 + st;
#pragma unroll
      for (int c = 0; c < 8; ++c) {
        const int vo = ((c * 2) * 4 + hst) * 512 + fb;
        const bf16x8 vhp = *(const bf16x8*)(lds + vo);
        const bf16x8 vlp = *(const bf16x8*)(lds + vo + 2048);
        const bf16x8 vhn = negf(vhp), vln = negf(vlp);
#pragma unroll
        for (int a = 0; a < 8; ++a) {
          const int k = a ^ c;
          const bf16x8 vh = SGN(a, c) ? vhn : vhp;
          const bf16x8 vl = SGN(a, c) ? vln : vlp;
          const bf16x8 ah = st ? A1h[a] : A0h[a];
          const bf16x8 al = st ? A1l[a] : A0l[a];
          acc[k] = mf(ah, vh, acc[k]);
          acc[k] = mf(al, vh, acc[k]);
          acc[k] = mf(ah, vl, acc[k]);
        }
      }
    }
    if (hf == 1) {
#pragma unroll
      for (int k = 0; k < 8; ++k)
        *(f32x4*)&scratch[(size_t)((rg * 8 + k) * 64 + l) * 4] = acc[k];
    }
    __syncthreads();
    if (hf == 0) {
      float* Ps = isG1 ? M.Pg1 + ((size_t)(sl * 32 + p)) * 8192
                       : M.Pg2 + ((size_t)(sl * 16 + p)) * 8192;
#pragma unroll
      for (int k = 0; k < 8; ++k) {
        acc[k] += *(const f32x4*)&scratch[(size_t)((rg * 8 + k) * 64 + l) * 4];
        *(f32x4*)&Ps[(size_t)((rg * 8 + k) * 64 + l) * 4] = acc[k];
      }
    }
    __syncthreads();
  };

  auto P2 = [&](int t, u16* Znh, u16* Znl, bool fin) {
    const int tg = bid * 512 + tid;
    if (!fin && tg < 8192) {  // S1_{t+2}: 32 panels x 256 thr
      const int pp = tg >> 8, th = tg & 255;
      const int idx0 = th * 8;
      const int kk = (idx0 >> 6) & 7, btw = idx0 >> 9, ln0 = idx0 & 63;
      const int lg0 = ln0 >> 4, m0 = ln0 & 15;
      f32x4 s4[8];
#pragma unroll
      for (int u = 0; u < 8; ++u) s4[u] = f32x4{0.f, 0.f, 0.f, 0.f};
      for (int ss = 0; ss < 4; ++ss) {
        const float* q =
            M.Pg1 + ((size_t)(ss * 32 + pp)) * 8192 + (size_t)idx0 * 4;
#pragma unroll
        for (int u = 0; u < 8; ++u) s4[u] += *(const f32x4*)&q[u * 4];
      }
      const int cbl = (pp * 16 + m0) >> 3;
#pragma unroll
      for (int q2 = 0; q2 < 4; ++q2) {
        const int b = btw * 16 + lg0 * 4 + q2;
        const float* ca = M.c1Z + (((size_t)kk * 64 + cbl) * 64 + b) * 8;
        const f32x4 c0 = *(const f32x4*)ca;
        const f32x4 c1v = *(const f32x4*)(ca + 4);
        u16x8 h8, l8;
#pragma unroll
        for (int u = 0; u < 8; ++u) {
          const float v = s4[u][q2] + (u < 4 ? c0[u] : c1v[u - 4]);
          const u16 hh = bf_rnd(v);
          h8[u] = hh;
          l8[u] = bf_rnd(v - bf_val(hh));
          if (t == 18)
            M.out1[((size_t)b * 512 + pp * 16 + m0 + u) * 8 + kk] = v;
        }
        const size_t zo = (((size_t)kk * 96 + 32 + cbl) * 64 + b) * 8;
        *(u16x8*)&Znh[zo] = h8;
        *(u16x8*)&Znl[zo] = l8;
      }
    }
    if (tg >= 8192 && tg < 12288) {  // S2: 16 panels x 256 thr
      const int pp = (tg - 8192) >> 8, th = tg & 255;
      const int idx0 = th * 8;
      const int kk = (idx0 >> 6) & 7, btw = idx0 >> 9, ln0 = idx0 & 63;
      const int lg0 = ln0 >> 4, m0 = ln0 & 15;
      f32x4 s4[8];
#pragma unroll
      for (int u = 0; u < 8; ++u) s4[u] = f32x4{0.f, 0.f, 0.f, 0.f};
      for (int ss = 0; ss < 6; ++ss) {
        const float* q =
            M.Pg2 + ((size_t)(ss * 16 + pp)) * 8192 + (size_t)idx0 * 4;
#pragma unroll
        for (int u = 0; u < 8; ++u) s4[u] += *(const f32x4*)&q[u * 4];
      }
      const int cbl = (pp * 16 + m0) >> 3;
#pragma unroll
      for (int q2 = 0; q2 < 4; ++q2) {
        const int b = btw * 16 + lg0 * 4 + q2;
        if (fin) {
#pragma unroll
          for (int u = 0; u < 8; ++u)
            M.out2[((size_t)b * 256 + pp * 16 + m0 + u) * 8 + kk] = s4[u][q2];
        } else {
          u16x8 h8, l8;
#pragma unroll
          for (int u = 0; u < 8; ++u) {
            const float v = s4[u][q2];
            const u16 hh = bf_rnd(v);
            h8[u] = hh;
            l8[u] = bf_rnd(v - bf_val(hh));
          }
          const size_t zo = (((size_t)kk * 96 + cbl) * 64 + b) * 8;
          *(u16x8*)&Znh[zo] = h8;
          *(u16x8*)&Znl[zo] = l8;
        }
      }
    }
  };

  for (int t = 0; t < 19; ++t) {
    const u16* Zch = (t & 1) ? M.Z1h : M.Z0h;
    const u16* Zcl = (t & 1) ? M.Z1l : M.Z0l;
    u16* Znh = (t & 1) ? M.Z0h : M.Z1h;
    u16* Znl = (t & 1) ? M.Z0l : M.Z1l;
    P1(Zch, Zcl);
    gbar(M.bar, baridx++);
    P2(t, Znh, Znl, false);
    gbar(M.bar, baridx++);
  }
  if (!isG1) P1(M.Z1h, M.Z1l);  // final g2: reads [S2_19 | S1_20]
  gbar(M.bar, baridx++);
  P2(19, nullptr, nullptr, true);
}

extern "C" void kernel_launch(void* const* d_in, const int* in_sizes, int n_in,
                              void* d_out, int out_size, void* d_ws,
                              size_t ws_size, hipStream_t stream) {
  const float* x = (const float*)d_in[0];
  const float* w1 = (const float*)d_in[1];
  const float* w2 = (const float*)d_in[2];

  float* out0 = (float*)d_out;
  float* out1 = out0 + 131072;
  float* out2 = out1 + 262144;

  char* W = (char*)d_ws;
  const size_t MB = 1ull << 20;
  u16* Vpk1 = (u16*)(W);
  u16* Vpk2 = (u16*)(W + 8 * MB);
  u16* Q1 = (u16*)(W + 14 * MB);
  u16* Q2 = (u16*)(W + 18 * MB);
  u16* Qc1 = (u16*)(W + 22 * MB);
  u16* P1h = (u16*)(W + 26 * MB);
  u16* P1l = (u16*)(W + 28 * MB);
  u16* P2h = (u16*)(W + 30 * MB);
  u16* P2l = (u16*)(W + 32 * MB);
  u16* Axh = (u16*)(W + 34 * MB);
  u16* Axl = (u16*)(W + 34 * MB + 262144);
  float* c1Z = (float*)(W + 35 * MB);
  float* V1raw = (float*)(W + 36 * MB);
  float* V2raw = (float*)(W + 44 * MB);
  u16* Z0h = (u16*)(W + 46 * MB);
  u16* Z0l = Z0h + 393216;
  u16* Z1h = Z0h + 786432;
  u16* Z1l = Z0h + 1179648;
  int* bar = (int*)(W + 49 * MB);
  int* ctr = bar + 8;
  float* Pg1 = (float*)(W + 50 * MB);
  float* Pg2 = (float*)(W + 54 * MB);
  float* co1P = (float*)(W + 58 * MB);
  float* co2P = (float*)(W + 74 * MB);
  float* rc1P = (float*)(W + 82 * MB);

  // D1: pack raw inputs
  pack_in<<<1346, 256, 0, stream>>>(x, w1, w2, P1h, P1l, Q1, Qc1, P2h, P2l, Q2,
                                    Axh, Axl, Z0h, Z0l, out0, bar, ctr);

  // D2: compose {V1raw, V2raw, c1 (-> c1Z + Z0.S1)}
  CRole co1{P1h, P1l, Q1, co1P, ctr, nullptr, nullptr, V1raw, nullptr,
            512, 256, 0, 32, 2, 512, 0};
  CRole co2{P2h, P2l, Q2, co2P, ctr, nullptr, nullptr, V2raw, nullptr,
            256, 512, 0, 16, 4, 256, 256};
  CRole rc1{Axh, Axl, Qc1, rc1P, ctr, Z0h, Z0l, nullptr, c1Z,
            64, 256, 0, 32, 2, 512, 320};
  pgemm<<<832, 256, 0, stream>>>(co1, co2, rc1, 512, 768);

  // D3: pack main-loop V panels (full index space: 262144 + 196608 entries)
  pack_main<<<1792, 256, 0, stream>>>(V1raw, V2raw, w2, Vpk1, Vpk2);

  // D4: persistent main loop (regular launch; 1 blk/CU via 96KB static LDS)
  MArgs marg{Vpk1, Vpk2, Z0h, Z0l, Z1h, Z1l, c1Z, Pg1, Pg2, out1, out2, bar};
  mainloop<<<dim3(NBLK), dim3(512), 0, stream>>>(marg);
}

// Round 7
// 756.387 us; speedup vs baseline: 6.1854x; 6.1854x over previous
//
#include <hip/hip_runtime.h>

typedef unsigned short u16;
typedef __attribute__((ext_vector_type(4))) float f32x4;
typedef __attribute__((ext_vector_type(8))) __bf16 bf16x8;
typedef __attribute__((ext_vector_type(8))) u16 u16x8;
typedef __attribute__((ext_vector_type(4))) unsigned int u32x4;

#define ALPHA_F 0.1f

// Cl(3,0): e_a * e_c = (-1)^p e_{a^c}  [validated R1-R6]
__device__ __host__ constexpr bool SGN(int a, int c) {
  return ((((c & 1) & (((a >> 1) ^ (a >> 2)) & 1)) ^
           (((c >> 1) & 1) & ((a >> 2) & 1))) != 0);
}
__device__ __host__ constexpr float REVF(int c) {
  const int r = (c & 1) + ((c >> 1) & 1) + ((c >> 2) & 1);
  return (r >= 2) ? -1.f : 1.f;
}
__device__ __forceinline__ u16 bf_rnd(float f) {
  unsigned u = __float_as_uint(f);
  return (u16)((u + 0x7FFFu + ((u >> 16) & 1u)) >> 16);
}
__device__ __forceinline__ float bf_val(u16 h) {
  return __uint_as_float(((unsigned)h) << 16);
}
__device__ __forceinline__ f32x4 mf(bf16x8 a, bf16x8 b, f32x4 c) {
  return __builtin_amdgcn_mfma_f32_16x16x32_bf16(a, b, c, 0, 0, 0);
}
__device__ __forceinline__ bf16x8 negf(bf16x8 v) {
  u16x8 u = __builtin_bit_cast(u16x8, v);
  const u16x8 m = {0x8000, 0x8000, 0x8000, 0x8000, 0x8000, 0x8000, 0x8000, 0x8000};
  u = u ^ m;
  return __builtin_bit_cast(bf16x8, u);
}

// ===========================================================================
// Compose pgemm (R4/R6-validated, one-time): blade-plane GEMM, 3-pass split
// bf16, K-split + counter-gated deterministic reduce. UNCHANGED.
// ===========================================================================
struct CRole {
  const u16 *Ahi, *Alo;
  const u16* Vpk;
  float* P;
  int* ctr;
  u16 *Zhi, *Zlo;
  float* outRaw;
  float* outZf;
  int AR, AN, acol0, npan, ksl, NC, ctrb;
};

__global__ __launch_bounds__(256) void pgemm(CRole r0, CRole r1, CRole r2,
                                             int n0, int n01) {
  __shared__ u16 Vs[2][16384];
  __shared__ int islast;

  CRole R;
  int r;
  const int bid = blockIdx.x;
  if (bid < n0) { R = r0; r = bid; }
  else if (bid < n01) { R = r1; r = bid - n0; }
  else { R = r2; r = bid - n01; }

  const int tid = threadIdx.x;
  const int w = tid >> 6, l = tid & 63;
  const int lg = l >> 4, lm = l & 15;

  const int sl = r % R.ksl;
  const int slot = r / R.ksl;
  const int p = slot % R.npan;
  const int rb = slot / R.npan;
  const int rowg = rb * 64 + w * 16 + lm;
  const int nchtot = R.ksl * 4;

  f32x4 acc[8];
#pragma unroll
  for (int i = 0; i < 8; ++i) acc[i] = f32x4{0.f, 0.f, 0.f, 0.f};

  auto VSTAGE = [&](int db, int ch) {
    const u16* src = R.Vpk + ((size_t)p * nchtot + sl * 4 + ch) * 8192;
#pragma unroll
    for (int i = 0; i < 4; ++i) {
      const int g = tid * 4 + i;
      const u32x4 v = *(const u32x4*)(src + (size_t)g * 8);
      u16* d = &Vs[db][(g >> 9) * 8192 + ((g >> 6) & 7) * 1024 +
                       ((g >> 4) & 3) * 128 + (g & 15) * 8];
      *(u32x4*)d = v;
      *(u32x4*)(d + 512) = v ^ 0x80008000u;
    }
  };
  auto ALOAD = [&](bf16x8* h, bf16x8* lo2, int ch) {
    const int coff = R.acol0 + (sl * 4 + ch) * 32 + lg * 8;
#pragma unroll
    for (int a = 0; a < 8; ++a) {
      const size_t o = ((size_t)(a * R.AR + rowg)) * R.AN + coff;
      h[a] = *(const bf16x8*)(R.Ahi + o);
      lo2[a] = *(const bf16x8*)(R.Alo + o);
    }
  };
  auto COMPUTE = [&](int db, const bf16x8* h, const bf16x8* lo2) {
    const int fb = lg * 128 + lm * 8;
#pragma unroll
    for (int c = 0; c < 8; ++c) {
      const bf16x8 vhp = *(const bf16x8*)&Vs[db][fb + c * 1024];
      const bf16x8 vhn = *(const bf16x8*)&Vs[db][fb + c * 1024 + 512];
      const bf16x8 vlp = *(const bf16x8*)&Vs[db][fb + 8192 + c * 1024];
      const bf16x8 vln = *(const bf16x8*)&Vs[db][fb + 8192 + c * 1024 + 512];
#pragma unroll
      for (int a = 0; a < 8; ++a) {
        const int k = a ^ c;
        const bf16x8 vh = SGN(a, c) ? vhn : vhp;
        const bf16x8 vl = SGN(a, c) ? vln : vlp;
        acc[k] = mf(h[a], vh, acc[k]);
        acc[k] = mf(lo2[a], vh, acc[k]);
        acc[k] = mf(h[a], vl, acc[k]);
      }
    }
  };

  bf16x8 Ah[8], Al8[8], Bh[8], Bl[8];
  VSTAGE(0, 0); ALOAD(Ah, Al8, 0);
  __syncthreads();
  VSTAGE(1, 1); ALOAD(Bh, Bl, 1);
  COMPUTE(0, Ah, Al8);
  __syncthreads();
  VSTAGE(0, 2); ALOAD(Ah, Al8, 2);
  COMPUTE(1, Bh, Bl);
  __syncthreads();
  VSTAGE(1, 3); ALOAD(Bh, Bl, 3);
  COMPUTE(0, Ah, Al8);
  __syncthreads();
  COMPUTE(1, Bh, Bl);

  float* Ps = R.P + ((size_t)slot * R.ksl + sl) * 8192;
#pragma unroll
  for (int k = 0; k < 8; ++k)
    *(f32x4*)&Ps[(size_t)((w * 8 + k) * 64 + l) * 4] = acc[k];

  __threadfence();
  __syncthreads();
  if (tid == 0) {
    int* cp = &R.ctr[R.ctrb + slot];
    const int c = atomicAdd(cp, 1);
    const int last = (c == R.ksl - 1);
    if (last) *cp = 0;
    islast = last;
  }
  __syncthreads();
  if (!islast) return;
  __threadfence();

  const int idx0 = tid * 8;
  f32x4 s4[8];
#pragma unroll
  for (int u = 0; u < 8; ++u) s4[u] = f32x4{0.f, 0.f, 0.f, 0.f};
  const float* Pb = R.P + (size_t)slot * R.ksl * 8192;
  for (int ss = 0; ss < R.ksl; ++ss) {
    const float* q = Pb + (size_t)ss * 8192 + (size_t)idx0 * 4;
#pragma unroll
    for (int u = 0; u < 8; ++u) s4[u] += *(const f32x4*)&q[u * 4];
  }

  const int kk = (idx0 >> 6) & 7, bt = idx0 >> 9, ln0 = idx0 & 63;
  const int lg0 = ln0 >> 4, m0 = ln0 & 15;

  if (R.outRaw) {
#pragma unroll
    for (int q2 = 0; q2 < 4; ++q2) {
      const int row = rb * 64 + bt * 16 + lg0 * 4 + q2;
#pragma unroll
      for (int u = 0; u < 8; ++u)
        R.outRaw[((size_t)row * R.NC + p * 16 + m0 + u) * 8 + kk] = s4[u][q2];
    }
  }
  if (R.Zhi) {
    const int cbl = (p * 16 + m0) >> 3;
#pragma unroll
    for (int q2 = 0; q2 < 4; ++q2) {
      const int b = bt * 16 + lg0 * 4 + q2;
      u16x8 h8, l8;
#pragma unroll
      for (int u = 0; u < 8; ++u) {
        const float v = s4[u][q2];
        const u16 hh = bf_rnd(v);
        h8[u] = hh;
        l8[u] = bf_rnd(v - bf_val(hh));
      }
      const size_t zo = (((size_t)kk * 96 + 32 + cbl) * 64 + b) * 8;
      *(u16x8*)&R.Zhi[zo] = h8;
      *(u16x8*)&R.Zlo[zo] = l8;
    }
  }
  if (R.outZf) {
    const int cbl = (p * 16 + m0) >> 3;
#pragma unroll
    for (int q2 = 0; q2 < 4; ++q2) {
      const int b = bt * 16 + lg0 * 4 + q2;
      float* dst = R.outZf + (((size_t)kk * 64 + cbl) * 64 + b) * 8;
      f32x4 v0 = {s4[0][q2], s4[1][q2], s4[2][q2], s4[3][q2]};
      f32x4 v1 = {s4[4][q2], s4[5][q2], s4[6][q2], s4[7][q2]};
      *(f32x4*)dst = v0;
      *(f32x4*)(dst + 4) = v1;
    }
  }
}

// ===========================================================================
// D1: pack raw inputs (R4/R6-validated). UNCHANGED.
// ===========================================================================
__global__ __launch_bounds__(256) void pack_in(
    const float* __restrict__ x, const float* __restrict__ w1,
    const float* __restrict__ w2, u16* P1h, u16* P1l, u16* Q1, u16* Qc1,
    u16* P2h, u16* P2l, u16* Q2, u16* Axh, u16* Axl, u16* Z0h, u16* Z0l,
    float* out0, int* bar, int* ctr) {
  const int t = blockIdx.x * 256 + threadIdx.x;
  if (t < 131072) {  // w1-space
    const int r = t >> 9, cc = t & 511;
    const float* s = w1 + ((size_t)r * 512 + cc) * 8;
    float v[8];
#pragma unroll
    for (int c = 0; c < 8; ++c) v[c] = s[c];
#pragma unroll
    for (int a = 0; a < 8; ++a) {
      const u16 h = bf_rnd(v[a]);
      P1h[((size_t)a * 512 + cc) * 256 + r] = h;
      P1l[((size_t)a * 512 + cc) * 256 + r] = bf_rnd(v[a] - bf_val(h));
    }
    const size_t ob = (size_t)((cc >> 4) * 8 + (r >> 5)) * 8192 +
                      ((r >> 3) & 3) * 128 + (cc & 15) * 8 + (r & 7);
#pragma unroll
    for (int c = 0; c < 8; ++c) {
      const float q1 = REVF(c) * v[c];
      u16 h = bf_rnd(q1);
      Q1[ob + c * 512] = h;
      Q1[ob + 4096 + c * 512] = bf_rnd(q1 - bf_val(h));
      const float qc = ALPHA_F * q1;
      h = bf_rnd(qc);
      Qc1[ob + c * 512] = h;
      Qc1[ob + 4096 + c * 512] = bf_rnd(qc - bf_val(h));
    }
  } else if (t < 262144) {  // w2-space
    const int u = t - 131072;
    const int r = u >> 8, c2 = u & 255;
    const float* s = w2 + ((size_t)r * 256 + c2) * 8;
    float v[8];
#pragma unroll
    for (int c = 0; c < 8; ++c) v[c] = s[c];
#pragma unroll
    for (int a = 0; a < 8; ++a) {
      const u16 h = bf_rnd(v[a]);
      P2h[((size_t)a * 256 + c2) * 512 + r] = h;
      P2l[((size_t)a * 256 + c2) * 512 + r] = bf_rnd(v[a] - bf_val(h));
    }
    const size_t ob2 = (size_t)((c2 >> 4) * 16 + (r >> 5)) * 8192 +
                       ((r >> 3) & 3) * 128 + (c2 & 15) * 8 + (r & 7);
#pragma unroll
    for (int c = 0; c < 8; ++c) {
      const float q2v = REVF(c) * v[c];
      const u16 h = bf_rnd(q2v);
      Q2[ob2 + c * 512] = h;
      Q2[ob2 + 4096 + c * 512] = bf_rnd(q2v - bf_val(h));
    }
  } else if (t < 278528) {  // x planes
    const int u = t - 262144;
    const int b = u >> 8, n = u & 255;
    const float* s = x + ((size_t)b * 256 + n) * 8;
#pragma unroll
    for (int a = 0; a < 8; ++a) {
      const u16 h = bf_rnd(s[a]);
      Axh[((size_t)a * 64 + b) * 256 + n] = h;
      Axl[((size_t)a * 64 + b) * 256 + n] = bf_rnd(s[a] - bf_val(h));
    }
  } else if (t < 311296) {  // out0 = x
    const int u = t - 278528;
    ((float4*)out0)[u] = ((const float4*)x)[u];
  } else if (t < 344064) {  // Z0 S2-region zero
    const int u = t - 311296;
    const int hl = u >> 14, i = u & 16383;
    const int a = i >> 11, j = i & 2047;
    const u16x8 z = {0, 0, 0, 0, 0, 0, 0, 0};
    u16* Z = hl ? Z0l : Z0h;
    *(u16x8*)&Z[(size_t)a * 49152 + (size_t)j * 8] = z;
  } else if (t < 344424) {
    const int i = t - 344064;
    if (i < 3) bar[i] = 0;
    else if (i < 355) ctr[i - 3] = 0;
  }
}

// ===========================================================================
// D3: pack composed operators into V-panel images (R6-validated layout):
//   Vpk[(p*slmul+sl)<<15][ ((c*2+hl)*4 + hst)*512 + lg*128 + lm*8 + e ]
// ===========================================================================
__global__ __launch_bounds__(256) void pack_main(const float* __restrict__ V1raw,
                                                 const float* __restrict__ V2raw,
                                                 const float* __restrict__ w2,
                                                 u16* Vpk1, u16* Vpk2) {
  const int t = blockIdx.x * 256 + threadIdx.x;
  if (t < 262144) {  // g1: (I - a*V1)
    const int lm = t & 15, lg = (t >> 4) & 3, s = (t >> 6) & 3;
    const int c = (t >> 8) & 7, sl = (t >> 11) & 3, p = t >> 13;  // p 0..31
    const int m = p * 16 + lm;
    u16 h8[8], l8[8];
#pragma unroll
    for (int e = 0; e < 8; ++e) {
      const int n = sl * 128 + s * 32 + lg * 8 + e;
      const float val = ((c == 0) && (n == m) ? 1.0f : 0.0f) -
                        ALPHA_F * V1raw[((size_t)n * 512 + m) * 8 + c];
      const u16 hh = bf_rnd(val);
      h8[e] = hh;
      l8[e] = bf_rnd(val - bf_val(hh));
    }
    u16* dst = Vpk1 + ((size_t)(p * 4 + sl) << 15) +
               ((c * 2) * 4 + s) * 512 + lg * 128 + lm * 8;
    *(u16x8*)dst = *(u16x8*)h8;
    *(u16x8*)(dst + 2048) = *(u16x8*)l8;
  } else if (t < 458752) {  // g2: [I - a*V2  |  a*rev(w2)]
    const int j = t - 262144;
    const int p = j / 12288, r2 = j % 12288;  // p 0..15
    const int sl = r2 >> 11, rest = r2 & 2047;
    const int c = (rest >> 8) & 7, s = (rest >> 6) & 3;
    const int lg = (rest >> 4) & 3, lm = rest & 15;
    const int m2 = p * 16 + lm;
    u16 h8[8], l8[8];
#pragma unroll
    for (int e = 0; e < 8; ++e) {
      const int n = sl * 128 + s * 32 + lg * 8 + e;
      float val;
      if (n < 256)
        val = ((c == 0) && (n == m2) ? 1.0f : 0.0f) -
              ALPHA_F * V2raw[((size_t)n * 256 + m2) * 8 + c];
      else
        val = ALPHA_F * REVF(c) * w2[((size_t)(n - 256) * 256 + m2) * 8 + c];
      const u16 hh = bf_rnd(val);
      h8[e] = hh;
      l8[e] = bf_rnd(val - bf_val(hh));
    }
    u16* dst = Vpk2 + ((size_t)(p * 6 + sl) << 15) +
               ((c * 2) * 4 + s) * 512 + lg * 128 + lm * 8;
    *(u16x8*)dst = *(u16x8*)h8;
    *(u16x8*)(dst + 2048) = *(u16x8*)l8;
  }
}

// ===========================================================================
// NEW: per-iteration pair kernel. NO fences, NO atomics, NO split-K.
// Block = 16 b-rows x 16 m-cols x 8 k, full K in-register per wave-slice.
// 8 waves = 8 K-slices; combined via one LDS panel sum (deterministic).
// g1 blocks (bid < n_g1): S1_{t+2} = S1 @ V1~ + c1   (K=512)
// g2 blocks: S2_{t+1} = [S2|S1'] @ Wcat               (K=768)
// ===========================================================================
struct IArgs {
  const u16 *Zch, *Zcl;
  u16 *Znh, *Znl;
  const u16 *Vpk1, *Vpk2;
  const float* c1Z;
  float *out1, *out2;
  int n_g1;
};

__global__ __launch_bounds__(512, 2) void iter_k(IArgs A, int t18, int fin) {
  __shared__ float pan[8][2048];  // 64KB: [wave][k:8][row:16][col:16]

  const int bid = blockIdx.x, tid = threadIdx.x;
  const int w = tid >> 6, l = tid & 63;
  const int lg = l >> 4, lm = l & 15;
  const bool g1 = bid < A.n_g1;
  const int rb = g1 ? bid : bid - A.n_g1;
  const int p = rb >> 2, bh = rb & 3;
  const int b0 = bh * 16;
  const int KW = g1 ? 64 : 96;   // K-extent per wave
  const int NW = g1 ? 2 : 3;     // 32-n windows per wave
  const int acb0 = g1 ? 32 : 0;  // A col-block base (S1 region vs full row)
  const u16* Vb = g1 ? A.Vpk1 : A.Vpk2;
  const int slmul = g1 ? 4 : 6;

  f32x4 acc[8];
#pragma unroll
  for (int k = 0; k < 8; ++k) acc[k] = f32x4{0.f, 0.f, 0.f, 0.f};

  for (int wi = 0; wi < NW; ++wi) {
    const int n0 = w * KW + wi * 32;
    const int sl = n0 >> 7, hst = (n0 >> 5) & 3;
    const u16* Vimg = Vb + ((size_t)(p * slmul + sl) << 15) + hst * 512 +
                      lg * 128 + lm * 8;
    // A-fragments: 8 blade planes, hi+lo, rows b0..b0+16, n-window n0..n0+32
    const size_t ao = ((size_t)(acb0 + (n0 >> 3) + lg) * 64 + b0 + lm) * 8;
    bf16x8 ah[8], al[8];
#pragma unroll
    for (int a = 0; a < 8; ++a) {
      ah[a] = *(const bf16x8*)(A.Zch + (size_t)a * 49152 + ao);
      al[a] = *(const bf16x8*)(A.Zcl + (size_t)a * 49152 + ao);
    }
#pragma unroll
    for (int c = 0; c < 8; ++c) {
      const bf16x8 vhp = *(const bf16x8*)(Vimg + (size_t)c * 4096);
      const bf16x8 vlp = *(const bf16x8*)(Vimg + (size_t)c * 4096 + 2048);
      const bf16x8 vhn = negf(vhp), vln = negf(vlp);
#pragma unroll
      for (int a = 0; a < 8; ++a) {
        const int k = a ^ c;
        const bf16x8 vh = SGN(a, c) ? vhn : vhp;
        const bf16x8 vl = SGN(a, c) ? vln : vlp;
        acc[k] = mf(ah[a], vh, acc[k]);
        acc[k] = mf(al[a], vh, acc[k]);
        acc[k] = mf(ah[a], vl, acc[k]);
      }
    }
  }

  // panel write: pan[w][k][row=lg*4+q][col=lm]
#pragma unroll
  for (int k = 0; k < 8; ++k)
#pragma unroll
    for (int q = 0; q < 4; ++q)
      pan[w][k * 256 + (lg * 4 + q) * 16 + lm] = acc[k][q];
  __syncthreads();

  // P2: 256 threads, deterministic 8-slice sum + epilogue
  if (tid < 256) {
    const int k = tid >> 5, row = (tid >> 1) & 15, ch = tid & 1;
    const int boff = k * 256 + row * 16 + ch * 8;
    f32x4 s0 = {0.f, 0.f, 0.f, 0.f}, s1 = {0.f, 0.f, 0.f, 0.f};
    for (int ss = 0; ss < 8; ++ss) {
      s0 += *(const f32x4*)&pan[ss][boff];
      s1 += *(const f32x4*)&pan[ss][boff + 4];
    }
    const int b = b0 + row;
    if (g1) {
      const float* ca =
          A.c1Z + (((size_t)k * 64 + p * 2 + ch) * 64 + b) * 8;
      s0 += *(const f32x4*)ca;
      s1 += *(const f32x4*)(ca + 4);
    }
    float v[8];
#pragma unroll
    for (int e = 0; e < 4; ++e) { v[e] = s0[e]; v[4 + e] = s1[e]; }
    if (!fin) {
      u16x8 h8, l8;
#pragma unroll
      for (int e = 0; e < 8; ++e) {
        const u16 hh = bf_rnd(v[e]);
        h8[e] = hh;
        l8[e] = bf_rnd(v[e] - bf_val(hh));
      }
      const size_t zo =
          (((size_t)k * 96 + (g1 ? 32 : 0) + p * 2 + ch) * 64 + b) * 8;
      *(u16x8*)&A.Znh[zo] = h8;
      *(u16x8*)&A.Znl[zo] = l8;
    }
    if (g1 && t18) {
#pragma unroll
      for (int e = 0; e < 8; ++e)
        A.out1[((size_t)b * 512 + p * 16 + ch * 8 + e) * 8 + k] = v[e];
    }
    if (!g1 && fin) {
#pragma unroll
      for (int e = 0; e < 8; ++e)
        A.out2[((size_t)b * 256 + p * 16 + ch * 8 + e) * 8 + k] = v[e];
    }
  }
}

extern "C" void kernel_launch(void* const* d_in, const int* in_sizes, int n_in,
                              void* d_out, int out_size, void* d_ws,
                              size_t ws_size, hipStream_t stream) {
  const float* x = (const float*)d_in[0];
  const float* w1 = (const float*)d_in[1];
  const float* w2 = (const float*)d_in[2];

  float* out0 = (float*)d_out;
  float* out1 = out0 + 131072;
  float* out2 = out1 + 262144;

  char* W = (char*)d_ws;
  const size_t MB = 1ull << 20;
  u16* Vpk1 = (u16*)(W);
  u16* Vpk2 = (u16*)(W + 8 * MB);
  u16* Q1 = (u16*)(W + 14 * MB);
  u16* Q2 = (u16*)(W + 18 * MB);
  u16* Qc1 = (u16*)(W + 22 * MB);
  u16* P1h = (u16*)(W + 26 * MB);
  u16* P1l = (u16*)(W + 28 * MB);
  u16* P2h = (u16*)(W + 30 * MB);
  u16* P2l = (u16*)(W + 32 * MB);
  u16* Axh = (u16*)(W + 34 * MB);
  u16* Axl = (u16*)(W + 34 * MB + 262144);
  float* c1Z = (float*)(W + 35 * MB);
  float* V1raw = (float*)(W + 36 * MB);
  float* V2raw = (float*)(W + 44 * MB);
  u16* Z0h = (u16*)(W + 46 * MB);
  u16* Z0l = Z0h + 393216;
  u16* Z1h = Z0h + 786432;
  u16* Z1l = Z0h + 1179648;
  int* bar = (int*)(W + 49 * MB);
  int* ctr = bar + 8;
  float* co1P = (float*)(W + 58 * MB);
  float* co2P = (float*)(W + 74 * MB);
  float* rc1P = (float*)(W + 82 * MB);

  // D1: pack raw inputs
  pack_in<<<1346, 256, 0, stream>>>(x, w1, w2, P1h, P1l, Q1, Qc1, P2h, P2l, Q2,
                                    Axh, Axl, Z0h, Z0l, out0, bar, ctr);

  // D2: compose {V1raw, V2raw, c1 (-> c1Z + Z0.S1)}
  CRole co1{P1h, P1l, Q1, co1P, ctr, nullptr, nullptr, V1raw, nullptr,
            512, 256, 0, 32, 2, 512, 0};
  CRole co2{P2h, P2l, Q2, co2P, ctr, nullptr, nullptr, V2raw, nullptr,
            256, 512, 0, 16, 4, 256, 256};
  CRole rc1{Axh, Axl, Qc1, rc1P, ctr, Z0h, Z0l, nullptr, c1Z,
            64, 256, 0, 32, 2, 512, 320};
  pgemm<<<832, 256, 0, stream>>>(co1, co2, rc1, 512, 768);

  // D3: pack main-loop V panel images
  pack_main<<<1792, 256, 0, stream>>>(V1raw, V2raw, w2, Vpk1, Vpk2);

  // D4..D22: 19 stream-ordered pair dispatches {g2_t, g1_{t+1}}
  for (int t = 0; t < 19; ++t) {
    IArgs ia;
    ia.Zch = (t & 1) ? Z1h : Z0h;
    ia.Zcl = (t & 1) ? Z1l : Z0l;
    ia.Znh = (t & 1) ? Z0h : Z1h;
    ia.Znl = (t & 1) ? Z0l : Z1l;
    ia.Vpk1 = Vpk1; ia.Vpk2 = Vpk2; ia.c1Z = c1Z;
    ia.out1 = out1; ia.out2 = nullptr;
    ia.n_g1 = 128;
    iter_k<<<192, 512, 0, stream>>>(ia, t == 18 ? 1 : 0, 0);
  }

  // D23: final g2_19 reads Z1 = [S2_19 | S1_20] -> out2 = S2_20
  {
    IArgs ia;
    ia.Zch = Z1h; ia.Zcl = Z1l;
    ia.Znh = Z0h; ia.Znl = Z0l;  // unused (fin)
    ia.Vpk1 = Vpk1; ia.Vpk2 = Vpk2; ia.c1Z = c1Z;
    ia.out1 = out1; ia.out2 = out2;
    ia.n_g1 = 0;
    iter_k<<<64, 512, 0, stream>>>(ia, 0, 1);
  }
}

// Round 8
// 576.856 us; speedup vs baseline: 8.1104x; 1.3112x over previous
//
#include <hip/hip_runtime.h>

typedef unsigned short u16;
typedef __attribute__((ext_vector_type(4))) float f32x4;
typedef __attribute__((ext_vector_type(8))) __bf16 bf16x8;
typedef __attribute__((ext_vector_type(8))) u16 u16x8;

#define ALPHA_F 0.1f

// Cl(3,0): e_a * e_c = (-1)^p e_{a^c}  [validated R1-R7]
__device__ __host__ constexpr bool SGN(int a, int c) {
  return ((((c & 1) & (((a >> 1) ^ (a >> 2)) & 1)) ^
           (((c >> 1) & 1) & ((a >> 2) & 1))) != 0);
}
__device__ __host__ constexpr float REVF(int c) {
  const int r = (c & 1) + ((c >> 1) & 1) + ((c >> 2) & 1);
  return (r >= 2) ? -1.f : 1.f;
}
__device__ __forceinline__ u16 bf_rnd(float f) {
  unsigned u = __float_as_uint(f);
  return (u16)((u + 0x7FFFu + ((u >> 16) & 1u)) >> 16);
}
__device__ __forceinline__ float bf_val(u16 h) {
  return __uint_as_float(((unsigned)h) << 16);
}
__device__ __forceinline__ f32x4 mf(bf16x8 a, bf16x8 b, f32x4 c) {
  return __builtin_amdgcn_mfma_f32_16x16x32_bf16(a, b, c, 0, 0, 0);
}
__device__ __forceinline__ bf16x8 negf(bf16x8 v) {
  u16x8 u = __builtin_bit_cast(u16x8, v);
  const u16x8 m = {0x8000, 0x8000, 0x8000, 0x8000, 0x8000, 0x8000, 0x8000, 0x8000};
  u = u ^ m;
  return __builtin_bit_cast(bf16x8, u);
}

// ===========================================================================
// D1: pack raw inputs. Q1/Q2/Qc1 are emitted directly in the V-image layout:
//   img[(p*slmul + sl)<<15] + c*4096 + hl*2048 + hst*512 + lgk*128 + col*8 + ek
// (p = col/16, sl = K/128, hst = (K/32)%4, lgk = (K/8)%4, ek = K%8).
// Wcat-bottom (alpha*rev(w2), K rows 256..767) goes straight into Vpk2 image.
// ===========================================================================
__global__ __launch_bounds__(256) void pack_in(
    const float* __restrict__ x, const float* __restrict__ w1,
    const float* __restrict__ w2, u16* P1h, u16* P1l, u16* Q1, u16* Qc1,
    u16* P2h, u16* P2l, u16* Q2, u16* Axh, u16* Axl, u16* Vpk2, u16* Z0h,
    u16* Z0l, float* out0) {
  const int t = blockIdx.x * 256 + threadIdx.x;
  if (t < 131072) {  // w1-space: r = m (0..255), cc = n' (0..511)
    const int r = t >> 9, cc = t & 511;
    const float* s = w1 + ((size_t)r * 512 + cc) * 8;
    float v[8];
#pragma unroll
    for (int c = 0; c < 8; ++c) v[c] = s[c];
#pragma unroll
    for (int a = 0; a < 8; ++a) {  // A planes for co1: [a][n'=cc][m=r]
      const u16 h = bf_rnd(v[a]);
      P1h[((size_t)a * 512 + cc) * 256 + r] = h;
      P1l[((size_t)a * 512 + cc) * 256 + r] = bf_rnd(v[a] - bf_val(h));
    }
    const size_t qo = (size_t)((cc >> 4) * 2 + (r >> 7)) * 32768 +
                      ((r >> 5) & 3) * 512 + ((r >> 3) & 3) * 128 +
                      (cc & 15) * 8 + (r & 7);
#pragma unroll
    for (int c = 0; c < 8; ++c) {
      const float q1 = REVF(c) * v[c];
      u16 h = bf_rnd(q1);
      Q1[qo + c * 4096] = h;
      Q1[qo + c * 4096 + 2048] = bf_rnd(q1 - bf_val(h));
      const float qc = ALPHA_F * q1;
      h = bf_rnd(qc);
      Qc1[qo + c * 4096] = h;
      Qc1[qo + c * 4096 + 2048] = bf_rnd(qc - bf_val(h));
    }
  } else if (t < 262144) {  // w2-space: r = m (0..511), c2 = j (0..255)
    const int u = t - 131072;
    const int r = u >> 8, c2 = u & 255;
    const float* s = w2 + ((size_t)r * 256 + c2) * 8;
    float v[8];
#pragma unroll
    for (int c = 0; c < 8; ++c) v[c] = s[c];
#pragma unroll
    for (int a = 0; a < 8; ++a) {  // A planes for co2: [a][j=c2][m=r]
      const u16 h = bf_rnd(v[a]);
      P2h[((size_t)a * 256 + c2) * 512 + r] = h;
      P2l[((size_t)a * 256 + c2) * 512 + r] = bf_rnd(v[a] - bf_val(h));
    }
    const size_t tail = ((r >> 5) & 3) * 512 + ((r >> 3) & 3) * 128 +
                        (c2 & 15) * 8 + (r & 7);
    const size_t qo = (size_t)((c2 >> 4) * 4 + (r >> 7)) * 32768 + tail;
    const size_t wo = (size_t)((c2 >> 4) * 6 + 2 + (r >> 7)) * 32768 + tail;
#pragma unroll
    for (int c = 0; c < 8; ++c) {
      const float q2 = REVF(c) * v[c];
      u16 h = bf_rnd(q2);
      Q2[qo + c * 4096] = h;
      Q2[qo + c * 4096 + 2048] = bf_rnd(q2 - bf_val(h));
      const float qw = ALPHA_F * q2;  // Wcat bottom: alpha*rev(w2)
      h = bf_rnd(qw);
      Vpk2[wo + c * 4096] = h;
      Vpk2[wo + c * 4096 + 2048] = bf_rnd(qw - bf_val(h));
    }
  } else if (t < 278528) {  // x planes [a][b][n]
    const int u = t - 262144;
    const int b = u >> 8, n = u & 255;
    const float* s = x + ((size_t)b * 256 + n) * 8;
#pragma unroll
    for (int a = 0; a < 8; ++a) {
      const u16 h = bf_rnd(s[a]);
      Axh[((size_t)a * 64 + b) * 256 + n] = h;
      Axl[((size_t)a * 64 + b) * 256 + n] = bf_rnd(s[a] - bf_val(h));
    }
  } else if (t < 311296) {  // out0 = x
    const int u = t - 278528;
    ((float4*)out0)[u] = ((const float4*)x)[u];
  } else if (t < 344064) {  // Z0 S2-region zero (chunks 0..31 of each plane)
    const int u = t - 311296;
    const int hl = u >> 14, i = u & 16383;
    const int a = i >> 11, j = i & 2047;
    const u16x8 z = {0, 0, 0, 0, 0, 0, 0, 0};
    u16* Z = hl ? Z0l : Z0h;
    *(u16x8*)&Z[(size_t)a * 49152 + (size_t)j * 8] = z;
  }
}

// ===========================================================================
// D2: composeK — iter_k-style compose, NO fences/atomics/split-K.
//  seg0 (1024 blk): V1raw = gp(w1-planes, rev w1) ; epilogue writes Vpk1 image
//                   as (I - alpha*V1) split hi/lo  [fused pack_main g1]
//  seg1 (256 blk):  V2raw ; epilogue writes Vpk2 image rows 0..255 (I - a*V2)
//  seg2 (128 blk):  c1 = gp(x, alpha*rev w1) ; epilogue -> c1Z fp32 + Z0 S1
// Block: 16 out-rows x 16 cols x 8 blades; 8 waves split K; LDS panel merge.
// ===========================================================================
__global__ __launch_bounds__(512, 2) void composeK(
    const u16* __restrict__ P1h, const u16* __restrict__ P1l,
    const u16* __restrict__ Q1, const u16* __restrict__ P2h,
    const u16* __restrict__ P2l, const u16* __restrict__ Q2,
    const u16* __restrict__ Axh, const u16* __restrict__ Axl,
    const u16* __restrict__ Qc1, u16* Vpk1, u16* Vpk2, u16* Z0h, u16* Z0l,
    float* c1Z) {
  __shared__ float pan[8][2048];

  const int bid = blockIdx.x, tid = threadIdx.x;
  const int w = tid >> 6, l = tid & 63;
  const int lg = l >> 4, lm = l & 15;

  int seg, rb, p;
  if (bid < 1024) { seg = 0; rb = bid >> 5; p = bid & 31; }
  else if (bid < 1280) { seg = 1; rb = (bid - 1024) >> 4; p = (bid - 1024) & 15; }
  else { seg = 2; rb = (bid - 1280) >> 5; p = (bid - 1280) & 31; }

  const u16* Ah_ = seg == 0 ? P1h : (seg == 1 ? P2h : Axh);
  const u16* Al_ = seg == 0 ? P1l : (seg == 1 ? P2l : Axl);
  const u16* Vb = seg == 0 ? Q1 : (seg == 1 ? Q2 : Qc1);
  const int AROW = seg == 0 ? 512 : (seg == 1 ? 256 : 64);
  const int KT = seg == 1 ? 512 : 256;   // K total
  const int NW = seg == 1 ? 2 : 1;       // 32-wide windows per wave
  const int slmul = seg == 1 ? 4 : 2;
  const int row = rb * 16 + lm;

  f32x4 acc[8];
#pragma unroll
  for (int k = 0; k < 8; ++k) acc[k] = f32x4{0.f, 0.f, 0.f, 0.f};

  for (int wi = 0; wi < NW; ++wi) {
    const int n0 = w * (NW * 32) + wi * 32;
    const int sl = n0 >> 7, hst = (n0 >> 5) & 3;
    const u16* Vimg =
        Vb + ((size_t)(p * slmul + sl) << 15) + hst * 512 + lg * 128 + lm * 8;
    bf16x8 ah[8], al[8];
#pragma unroll
    for (int a = 0; a < 8; ++a) {
      const size_t o = ((size_t)(a * AROW + row)) * KT + n0 + lg * 8;
      ah[a] = *(const bf16x8*)(Ah_ + o);
      al[a] = *(const bf16x8*)(Al_ + o);
    }
#pragma unroll
    for (int c = 0; c < 8; ++c) {
      const bf16x8 vhp = *(const bf16x8*)(Vimg + (size_t)c * 4096);
      const bf16x8 vlp = *(const bf16x8*)(Vimg + (size_t)c * 4096 + 2048);
      const bf16x8 vhn = negf(vhp), vln = negf(vlp);
#pragma unroll
      for (int a = 0; a < 8; ++a) {
        const int k = a ^ c;
        const bf16x8 vh = SGN(a, c) ? vhn : vhp;
        const bf16x8 vl = SGN(a, c) ? vln : vlp;
        acc[k] = mf(ah[a], vh, acc[k]);
        acc[k] = mf(al[a], vh, acc[k]);
        acc[k] = mf(ah[a], vl, acc[k]);
      }
    }
  }

#pragma unroll
  for (int k = 0; k < 8; ++k)
#pragma unroll
    for (int q = 0; q < 4; ++q)
      pan[w][k * 256 + (lg * 4 + q) * 16 + lm] = acc[k][q];
  __syncthreads();

  if (tid < 256) {
    const int k = tid >> 5, rw = (tid >> 1) & 15, ch = tid & 1;
    const int boff = k * 256 + rw * 16 + ch * 8;
    f32x4 s0 = {0.f, 0.f, 0.f, 0.f}, s1 = {0.f, 0.f, 0.f, 0.f};
    for (int ss = 0; ss < 8; ++ss) {
      s0 += *(const f32x4*)&pan[ss][boff];
      s1 += *(const f32x4*)&pan[ss][boff + 4];
    }
    float v[8];
#pragma unroll
    for (int e = 0; e < 4; ++e) { v[e] = s0[e]; v[4 + e] = s1[e]; }
    const int n = rb * 16 + rw;  // compose out-row = main-loop K index

    if (seg <= 1) {  // fused operator pack: (I - alpha*V) -> V image hi/lo
      u16* base = seg == 0 ? Vpk1 : Vpk2;
      const int blk = (seg == 0 ? p * 4 : p * 6) + (n >> 7);
      u16* d = base + ((size_t)blk << 15) + (size_t)k * 4096 +
               ((n >> 5) & 3) * 512 + ((n >> 3) & 3) * 128 + (n & 7);
#pragma unroll
      for (int e = 0; e < 8; ++e) {
        const int m = p * 16 + ch * 8 + e;
        const float val = ((k == 0) && (n == m) ? 1.0f : 0.0f) - ALPHA_F * v[e];
        const u16 hh = bf_rnd(val);
        d[(size_t)(ch * 8 + e) * 8] = hh;
        d[2048 + (size_t)(ch * 8 + e) * 8] = bf_rnd(val - bf_val(hh));
      }
    } else {  // rc1: c1Z fp32 + Z0 S1 bf16 hi/lo
      const int b = n;  // 0..63
      float* cp_ = c1Z + (((size_t)k * 64 + p * 2 + ch) * 64 + b) * 8;
      u16x8 h8, l8;
#pragma unroll
      for (int e = 0; e < 8; ++e) {
        cp_[e] = v[e];
        const u16 hh = bf_rnd(v[e]);
        h8[e] = hh;
        l8[e] = bf_rnd(v[e] - bf_val(hh));
      }
      const size_t zo = (((size_t)k * 96 + 32 + p * 2 + ch) * 64 + b) * 8;
      *(u16x8*)&Z0h[zo] = h8;
      *(u16x8*)&Z0l[zo] = l8;
    }
  }
}

// ===========================================================================
// Main-loop pair kernel (R7-validated, UNCHANGED). No fences/atomics/split-K.
// ===========================================================================
struct IArgs {
  const u16 *Zch, *Zcl;
  u16 *Znh, *Znl;
  const u16 *Vpk1, *Vpk2;
  const float* c1Z;
  float *out1, *out2;
  int n_g1;
};

__global__ __launch_bounds__(512, 2) void iter_k(IArgs A, int t18, int fin) {
  __shared__ float pan[8][2048];

  const int bid = blockIdx.x, tid = threadIdx.x;
  const int w = tid >> 6, l = tid & 63;
  const int lg = l >> 4, lm = l & 15;
  const bool g1 = bid < A.n_g1;
  const int rb = g1 ? bid : bid - A.n_g1;
  const int p = rb >> 2, bh = rb & 3;
  const int b0 = bh * 16;
  const int KW = g1 ? 64 : 96;
  const int NW = g1 ? 2 : 3;
  const int acb0 = g1 ? 32 : 0;
  const u16* Vb = g1 ? A.Vpk1 : A.Vpk2;
  const int slmul = g1 ? 4 : 6;

  f32x4 acc[8];
#pragma unroll
  for (int k = 0; k < 8; ++k) acc[k] = f32x4{0.f, 0.f, 0.f, 0.f};

  for (int wi = 0; wi < NW; ++wi) {
    const int n0 = w * KW + wi * 32;
    const int sl = n0 >> 7, hst = (n0 >> 5) & 3;
    const u16* Vimg = Vb + ((size_t)(p * slmul + sl) << 15) + hst * 512 +
                      lg * 128 + lm * 8;
    const size_t ao = ((size_t)(acb0 + (n0 >> 3) + lg) * 64 + b0 + lm) * 8;
    bf16x8 ah[8], al[8];
#pragma unroll
    for (int a = 0; a < 8; ++a) {
      ah[a] = *(const bf16x8*)(A.Zch + (size_t)a * 49152 + ao);
      al[a] = *(const bf16x8*)(A.Zcl + (size_t)a * 49152 + ao);
    }
#pragma unroll
    for (int c = 0; c < 8; ++c) {
      const bf16x8 vhp = *(const bf16x8*)(Vimg + (size_t)c * 4096);
      const bf16x8 vlp = *(const bf16x8*)(Vimg + (size_t)c * 4096 + 2048);
      const bf16x8 vhn = negf(vhp), vln = negf(vlp);
#pragma unroll
      for (int a = 0; a < 8; ++a) {
        const int k = a ^ c;
        const bf16x8 vh = SGN(a, c) ? vhn : vhp;
        const bf16x8 vl = SGN(a, c) ? vln : vlp;
        acc[k] = mf(ah[a], vh, acc[k]);
        acc[k] = mf(al[a], vh, acc[k]);
        acc[k] = mf(ah[a], vl, acc[k]);
      }
    }
  }

#pragma unroll
  for (int k = 0; k < 8; ++k)
#pragma unroll
    for (int q = 0; q < 4; ++q)
      pan[w][k * 256 + (lg * 4 + q) * 16 + lm] = acc[k][q];
  __syncthreads();

  if (tid < 256) {
    const int k = tid >> 5, row = (tid >> 1) & 15, ch = tid & 1;
    const int boff = k * 256 + row * 16 + ch * 8;
    f32x4 s0 = {0.f, 0.f, 0.f, 0.f}, s1 = {0.f, 0.f, 0.f, 0.f};
    for (int ss = 0; ss < 8; ++ss) {
      s0 += *(const f32x4*)&pan[ss][boff];
      s1 += *(const f32x4*)&pan[ss][boff + 4];
    }
    const int b = b0 + row;
    if (g1) {
      const float* ca = A.c1Z + (((size_t)k * 64 + p * 2 + ch) * 64 + b) * 8;
      s0 += *(const f32x4*)ca;
      s1 += *(const f32x4*)(ca + 4);
    }
    float v[8];
#pragma unroll
    for (int e = 0; e < 4; ++e) { v[e] = s0[e]; v[4 + e] = s1[e]; }
    if (!fin) {
      u16x8 h8, l8;
#pragma unroll
      for (int e = 0; e < 8; ++e) {
        const u16 hh = bf_rnd(v[e]);
        h8[e] = hh;
        l8[e] = bf_rnd(v[e] - bf_val(hh));
      }
      const size_t zo =
          (((size_t)k * 96 + (g1 ? 32 : 0) + p * 2 + ch) * 64 + b) * 8;
      *(u16x8*)&A.Znh[zo] = h8;
      *(u16x8*)&A.Znl[zo] = l8;
    }
    if (g1 && t18) {
#pragma unroll
      for (int e = 0; e < 8; ++e)
        A.out1[((size_t)b * 512 + p * 16 + ch * 8 + e) * 8 + k] = v[e];
    }
    if (!g1 && fin) {
#pragma unroll
      for (int e = 0; e < 8; ++e)
        A.out2[((size_t)b * 256 + p * 16 + ch * 8 + e) * 8 + k] = v[e];
    }
  }
}

extern "C" void kernel_launch(void* const* d_in, const int* in_sizes, int n_in,
                              void* d_out, int out_size, void* d_ws,
                              size_t ws_size, hipStream_t stream) {
  const float* x = (const float*)d_in[0];
  const float* w1 = (const float*)d_in[1];
  const float* w2 = (const float*)d_in[2];

  float* out0 = (float*)d_out;
  float* out1 = out0 + 131072;
  float* out2 = out1 + 262144;

  char* W = (char*)d_ws;
  const size_t MB = 1ull << 20;
  u16* Vpk1 = (u16*)(W);                 // 8 MB (32p x 4sl x 64KB)
  u16* Vpk2 = (u16*)(W + 8 * MB);        // 6 MB (16p x 6sl)
  u16* Q1 = (u16*)(W + 14 * MB);         // 4 MB (32p x 2sl)
  u16* Q2 = (u16*)(W + 18 * MB);         // 4 MB (16p x 4sl)
  u16* Qc1 = (u16*)(W + 22 * MB);        // 4 MB
  u16* P1h = (u16*)(W + 26 * MB);        // 2 MB each
  u16* P1l = (u16*)(W + 28 * MB);
  u16* P2h = (u16*)(W + 30 * MB);
  u16* P2l = (u16*)(W + 32 * MB);
  u16* Axh = (u16*)(W + 34 * MB);        // 256 KB each
  u16* Axl = (u16*)(W + 34 * MB + 262144);
  float* c1Z = (float*)(W + 35 * MB);    // 1 MB
  u16* Z0h = (u16*)(W + 46 * MB);        // 768 KB each
  u16* Z0l = Z0h + 393216;
  u16* Z1h = Z0h + 786432;
  u16* Z1l = Z0h + 1179648;

  // D1: pack raw inputs (Q/Wcat-bottom straight into V-image layouts)
  pack_in<<<1344, 256, 0, stream>>>(x, w1, w2, P1h, P1l, Q1, Qc1, P2h, P2l, Q2,
                                    Axh, Axl, Vpk2, Z0h, Z0l, out0);

  // D2: compose + fused operator pack (no atomics, no fences)
  composeK<<<1408, 512, 0, stream>>>(P1h, P1l, Q1, P2h, P2l, Q2, Axh, Axl, Qc1,
                                     Vpk1, Vpk2, Z0h, Z0l, c1Z);

  // D3..D21: 19 stream-ordered pair dispatches {g2_t, g1_{t+1}}
  for (int t = 0; t < 19; ++t) {
    IArgs ia;
    ia.Zch = (t & 1) ? Z1h : Z0h;
    ia.Zcl = (t & 1) ? Z1l : Z0l;
    ia.Znh = (t & 1) ? Z0h : Z1h;
    ia.Znl = (t & 1) ? Z0l : Z1l;
    ia.Vpk1 = Vpk1; ia.Vpk2 = Vpk2; ia.c1Z = c1Z;
    ia.out1 = out1; ia.out2 = nullptr;
    ia.n_g1 = 128;
    iter_k<<<192, 512, 0, stream>>>(ia, t == 18 ? 1 : 0, 0);
  }

  // D22: final g2_19 reads Z1 = [S2_19 | S1_20] -> out2 = S2_20
  {
    IArgs ia;
    ia.Zch = Z1h; ia.Zcl = Z1l;
    ia.Znh = Z0h; ia.Znl = Z0l;  // unused (fin)
    ia.Vpk1 = Vpk1; ia.Vpk2 = Vpk2; ia.c1Z = c1Z;
    ia.out1 = out1; ia.out2 = out2;
    ia.n_g1 = 0;
    iter_k<<<64, 512, 0, stream>>>(ia, 0, 1);
  }
}

// Round 9
// 465.606 us; speedup vs baseline: 10.0483x; 1.2389x over previous
//
#include <hip/hip_runtime.h>

typedef unsigned short u16;
typedef __attribute__((ext_vector_type(4))) float f32x4;
typedef __attribute__((ext_vector_type(8))) __bf16 bf16x8;
typedef __attribute__((ext_vector_type(8))) u16 u16x8;

#define ALPHA_F 0.1f

// Cl(3,0): e_a * e_c = (-1)^p e_{a^c}  [validated R1-R8]
__device__ __host__ constexpr bool SGN(int a, int c) {
  return ((((c & 1) & (((a >> 1) ^ (a >> 2)) & 1)) ^
           (((c >> 1) & 1) & ((a >> 2) & 1))) != 0);
}
__device__ __host__ constexpr float REVF(int c) {
  const int r = (c & 1) + ((c >> 1) & 1) + ((c >> 2) & 1);
  return (r >= 2) ? -1.f : 1.f;
}
__device__ __forceinline__ u16 bf_rnd(float f) {
  unsigned u = __float_as_uint(f);
  return (u16)((u + 0x7FFFu + ((u >> 16) & 1u)) >> 16);
}
__device__ __forceinline__ float bf_val(u16 h) {
  return __uint_as_float(((unsigned)h) << 16);
}
__device__ __forceinline__ f32x4 mf(bf16x8 a, bf16x8 b, f32x4 c) {
  return __builtin_amdgcn_mfma_f32_16x16x32_bf16(a, b, c, 0, 0, 0);
}
__device__ __forceinline__ bf16x8 negf(bf16x8 v) {
  u16x8 u = __builtin_bit_cast(u16x8, v);
  const u16x8 m = {0x8000, 0x8000, 0x8000, 0x8000, 0x8000, 0x8000, 0x8000, 0x8000};
  u = u ^ m;
  return __builtin_bit_cast(bf16x8, u);
}

// ===========================================================================
// D1: pack raw inputs. Q images in V-image layout (validated R8). P blade
// planes now packed via r-fast ranges (coalesced 2B writes).
// ===========================================================================
__global__ __launch_bounds__(256) void pack_in(
    const float* __restrict__ x, const float* __restrict__ w1,
    const float* __restrict__ w2, u16* P1h, u16* P1l, u16* Q1, u16* Qc1,
    u16* P2h, u16* P2l, u16* Q2, u16* Axh, u16* Axl, u16* Vpk2, u16* Z0h,
    u16* Z0l, float* out0) {
  const int t = blockIdx.x * 256 + threadIdx.x;
  if (t < 131072) {  // Q1 + Qc1 (cc-fast): r = m, cc = n'
    const int r = t >> 9, cc = t & 511;
    const float* s = w1 + ((size_t)r * 512 + cc) * 8;
    float v[8];
#pragma unroll
    for (int c = 0; c < 8; ++c) v[c] = s[c];
    const size_t qo = (size_t)((cc >> 4) * 2 + (r >> 7)) * 32768 +
                      ((r >> 5) & 3) * 512 + ((r >> 3) & 3) * 128 +
                      (cc & 15) * 8 + (r & 7);
#pragma unroll
    for (int c = 0; c < 8; ++c) {
      const float q1 = REVF(c) * v[c];
      u16 h = bf_rnd(q1);
      Q1[qo + c * 4096] = h;
      Q1[qo + c * 4096 + 2048] = bf_rnd(q1 - bf_val(h));
      const float qc = ALPHA_F * q1;
      h = bf_rnd(qc);
      Qc1[qo + c * 4096] = h;
      Qc1[qo + c * 4096 + 2048] = bf_rnd(qc - bf_val(h));
    }
  } else if (t < 262144) {  // Q2 + Wcat-bottom (c2-fast): r = m, c2 = j
    const int u = t - 131072;
    const int r = u >> 8, c2 = u & 255;
    const float* s = w2 + ((size_t)r * 256 + c2) * 8;
    float v[8];
#pragma unroll
    for (int c = 0; c < 8; ++c) v[c] = s[c];
    const size_t tail = ((r >> 5) & 3) * 512 + ((r >> 3) & 3) * 128 +
                        (c2 & 15) * 8 + (r & 7);
    const size_t qo = (size_t)((c2 >> 4) * 4 + (r >> 7)) * 32768 + tail;
    const size_t wo = (size_t)((c2 >> 4) * 6 + 2 + (r >> 7)) * 32768 + tail;
#pragma unroll
    for (int c = 0; c < 8; ++c) {
      const float q2 = REVF(c) * v[c];
      u16 h = bf_rnd(q2);
      Q2[qo + c * 4096] = h;
      Q2[qo + c * 4096 + 2048] = bf_rnd(q2 - bf_val(h));
      const float qw = ALPHA_F * q2;
      h = bf_rnd(qw);
      Vpk2[wo + c * 4096] = h;
      Vpk2[wo + c * 4096 + 2048] = bf_rnd(qw - bf_val(h));
    }
  } else if (t < 393216) {  // P1 planes, r-fast (coalesced writes)
    const int u = t - 262144;
    const int r = u & 255, cc = u >> 8;
    const float* s = w1 + ((size_t)r * 512 + cc) * 8;
#pragma unroll
    for (int a = 0; a < 8; ++a) {
      const float v = s[a];
      const u16 h = bf_rnd(v);
      P1h[((size_t)a * 512 + cc) * 256 + r] = h;
      P1l[((size_t)a * 512 + cc) * 256 + r] = bf_rnd(v - bf_val(h));
    }
  } else if (t < 524288) {  // P2 planes, r-fast
    const int u = t - 393216;
    const int r = u & 511, c2 = u >> 9;
    const float* s = w2 + ((size_t)r * 256 + c2) * 8;
#pragma unroll
    for (int a = 0; a < 8; ++a) {
      const float v = s[a];
      const u16 h = bf_rnd(v);
      P2h[((size_t)a * 256 + c2) * 512 + r] = h;
      P2l[((size_t)a * 256 + c2) * 512 + r] = bf_rnd(v - bf_val(h));
    }
  } else if (t < 540672) {  // x planes [a][b][n]
    const int u = t - 524288;
    const int b = u >> 8, n = u & 255;
    const float* s = x + ((size_t)b * 256 + n) * 8;
#pragma unroll
    for (int a = 0; a < 8; ++a) {
      const u16 h = bf_rnd(s[a]);
      Axh[((size_t)a * 64 + b) * 256 + n] = h;
      Axl[((size_t)a * 64 + b) * 256 + n] = bf_rnd(s[a] - bf_val(h));
    }
  } else if (t < 573440) {  // out0 = x
    const int u = t - 540672;
    ((float4*)out0)[u] = ((const float4*)x)[u];
  } else if (t < 606208) {  // Z0 S2-region zero
    const int u = t - 573440;
    const int hl = u >> 14, i = u & 16383;
    const int a = i >> 11, j = i & 2047;
    const u16x8 z = {0, 0, 0, 0, 0, 0, 0, 0};
    u16* Z = hl ? Z0l : Z0h;
    *(u16x8*)&Z[(size_t)a * 49152 + (size_t)j * 8] = z;
  }
}

// ===========================================================================
// D2: composeK (validated R8 core). Heavy seg1 blocks first for makespan.
// ===========================================================================
__global__ __launch_bounds__(512, 2) void composeK(
    const u16* __restrict__ P1h, const u16* __restrict__ P1l,
    const u16* __restrict__ Q1, const u16* __restrict__ P2h,
    const u16* __restrict__ P2l, const u16* __restrict__ Q2,
    const u16* __restrict__ Axh, const u16* __restrict__ Axl,
    const u16* __restrict__ Qc1, u16* Vpk1, u16* Vpk2, u16* Z0h, u16* Z0l,
    float* c1Z) {
  __shared__ float pan[8][2048];

  const int bid = blockIdx.x, tid = threadIdx.x;
  const int w = tid >> 6, l = tid & 63;
  const int lg = l >> 4, lm = l & 15;

  int seg, rb, p;
  if (bid < 256) { seg = 1; rb = bid >> 4; p = bid & 15; }
  else if (bid < 1280) { seg = 0; rb = (bid - 256) >> 5; p = (bid - 256) & 31; }
  else { seg = 2; rb = (bid - 1280) >> 5; p = (bid - 1280) & 31; }

  const u16* Ah_ = seg == 0 ? P1h : (seg == 1 ? P2h : Axh);
  const u16* Al_ = seg == 0 ? P1l : (seg == 1 ? P2l : Axl);
  const u16* Vb = seg == 0 ? Q1 : (seg == 1 ? Q2 : Qc1);
  const int AROW = seg == 0 ? 512 : (seg == 1 ? 256 : 64);
  const int KT = seg == 1 ? 512 : 256;
  const int NW = seg == 1 ? 2 : 1;
  const int slmul = seg == 1 ? 4 : 2;
  const int row = rb * 16 + lm;

  f32x4 acc[8];
#pragma unroll
  for (int k = 0; k < 8; ++k) acc[k] = f32x4{0.f, 0.f, 0.f, 0.f};

  for (int wi = 0; wi < NW; ++wi) {
    const int n0 = w * (NW * 32) + wi * 32;
    const int sl = n0 >> 7, hst = (n0 >> 5) & 3;
    const u16* Vimg =
        Vb + ((size_t)(p * slmul + sl) << 15) + hst * 512 + lg * 128 + lm * 8;
    bf16x8 ah[8], al[8];
#pragma unroll
    for (int a = 0; a < 8; ++a) {
      const size_t o = ((size_t)(a * AROW + row)) * KT + n0 + lg * 8;
      ah[a] = *(const bf16x8*)(Ah_ + o);
      al[a] = *(const bf16x8*)(Al_ + o);
    }
#pragma unroll
    for (int c = 0; c < 8; ++c) {
      const bf16x8 vhp = *(const bf16x8*)(Vimg + (size_t)c * 4096);
      const bf16x8 vlp = *(const bf16x8*)(Vimg + (size_t)c * 4096 + 2048);
      const bf16x8 vhn = negf(vhp), vln = negf(vlp);
#pragma unroll
      for (int a = 0; a < 8; ++a) {
        const int k = a ^ c;
        const bf16x8 vh = SGN(a, c) ? vhn : vhp;
        const bf16x8 vl = SGN(a, c) ? vln : vlp;
        acc[k] = mf(ah[a], vh, acc[k]);
        acc[k] = mf(al[a], vh, acc[k]);
        acc[k] = mf(ah[a], vl, acc[k]);
      }
    }
  }

#pragma unroll
  for (int k = 0; k < 8; ++k)
#pragma unroll
    for (int q = 0; q < 4; ++q)
      pan[w][k * 256 + (lg * 4 + q) * 16 + lm] = acc[k][q];
  __syncthreads();

  if (tid < 256) {
    const int k = tid >> 5, rw = (tid >> 1) & 15, ch = tid & 1;
    const int boff = k * 256 + rw * 16 + ch * 8;
    f32x4 s0 = {0.f, 0.f, 0.f, 0.f}, s1 = {0.f, 0.f, 0.f, 0.f};
    for (int ss = 0; ss < 8; ++ss) {
      s0 += *(const f32x4*)&pan[ss][boff];
      s1 += *(const f32x4*)&pan[ss][boff + 4];
    }
    float v[8];
#pragma unroll
    for (int e = 0; e < 4; ++e) { v[e] = s0[e]; v[4 + e] = s1[e]; }
    const int n = rb * 16 + rw;

    if (seg <= 1) {
      u16* base = seg == 0 ? Vpk1 : Vpk2;
      const int blk = (seg == 0 ? p * 4 : p * 6) + (n >> 7);
      u16* d = base + ((size_t)blk << 15) + (size_t)k * 4096 +
               ((n >> 5) & 3) * 512 + ((n >> 3) & 3) * 128 + (n & 7);
#pragma unroll
      for (int e = 0; e < 8; ++e) {
        const int m = p * 16 + ch * 8 + e;
        const float val = ((k == 0) && (n == m) ? 1.0f : 0.0f) - ALPHA_F * v[e];
        const u16 hh = bf_rnd(val);
        d[(size_t)(ch * 8 + e) * 8] = hh;
        d[2048 + (size_t)(ch * 8 + e) * 8] = bf_rnd(val - bf_val(hh));
      }
    } else {
      const int b = n;
      float* cp_ = c1Z + (((size_t)k * 64 + p * 2 + ch) * 64 + b) * 8;
      u16x8 h8, l8;
#pragma unroll
      for (int e = 0; e < 8; ++e) {
        cp_[e] = v[e];
        const u16 hh = bf_rnd(v[e]);
        h8[e] = hh;
        l8[e] = bf_rnd(v[e] - bf_val(hh));
      }
      const size_t zo = (((size_t)k * 96 + 32 + p * 2 + ch) * 64 + b) * 8;
      *(u16x8*)&Z0h[zo] = h8;
      *(u16x8*)&Z0l[zo] = l8;
    }
  }
}

// ===========================================================================
// Main-loop pair kernel, templated on role: constexpr NW -> full unroll,
// load hoisting across windows. Arithmetic order IDENTICAL to R7/R8.
// ===========================================================================
struct IArgs {
  const u16 *Zch, *Zcl;
  u16 *Znh, *Znl;
  const u16 *Vpk1, *Vpk2;
  const float* c1Z;
  float *out1, *out2;
  int n_g1;
};

template <bool G1>
__device__ __forceinline__ void iter_body(const IArgs& A, int t18, int fin,
                                          float (*pan)[2048]) {
  const int bid = blockIdx.x, tid = threadIdx.x;
  const int w = tid >> 6, l = tid & 63;
  const int lg = l >> 4, lm = l & 15;
  const int rb = G1 ? bid : bid - A.n_g1;
  const int p = rb >> 2, bh = rb & 3;
  const int b0 = bh * 16;
  constexpr int KW = G1 ? 64 : 96;
  constexpr int NW = G1 ? 2 : 3;
  constexpr int acb0 = G1 ? 32 : 0;
  constexpr int slmul = G1 ? 4 : 6;
  const u16* Vb = G1 ? A.Vpk1 : A.Vpk2;

  f32x4 acc[8];
#pragma unroll
  for (int k = 0; k < 8; ++k) acc[k] = f32x4{0.f, 0.f, 0.f, 0.f};

#pragma unroll
  for (int wi = 0; wi < NW; ++wi) {
    const int n0 = w * KW + wi * 32;
    const int sl = n0 >> 7, hst = (n0 >> 5) & 3;
    const u16* Vimg = Vb + ((size_t)(p * slmul + sl) << 15) + hst * 512 +
                      lg * 128 + lm * 8;
    const size_t ao = ((size_t)(acb0 + (n0 >> 3) + lg) * 64 + b0 + lm) * 8;
    bf16x8 ah[8], al[8];
#pragma unroll
    for (int a = 0; a < 8; ++a) {
      ah[a] = *(const bf16x8*)(A.Zch + (size_t)a * 49152 + ao);
      al[a] = *(const bf16x8*)(A.Zcl + (size_t)a * 49152 + ao);
    }
#pragma unroll
    for (int c = 0; c < 8; ++c) {
      const bf16x8 vhp = *(const bf16x8*)(Vimg + (size_t)c * 4096);
      const bf16x8 vlp = *(const bf16x8*)(Vimg + (size_t)c * 4096 + 2048);
      const bf16x8 vhn = negf(vhp), vln = negf(vlp);
#pragma unroll
      for (int a = 0; a < 8; ++a) {
        const int k = a ^ c;
        const bf16x8 vh = SGN(a, c) ? vhn : vhp;
        const bf16x8 vl = SGN(a, c) ? vln : vlp;
        acc[k] = mf(ah[a], vh, acc[k]);
        acc[k] = mf(al[a], vh, acc[k]);
        acc[k] = mf(ah[a], vl, acc[k]);
      }
    }
  }

#pragma unroll
  for (int k = 0; k < 8; ++k)
#pragma unroll
    for (int q = 0; q < 4; ++q)
      pan[w][k * 256 + (lg * 4 + q) * 16 + lm] = acc[k][q];
  __syncthreads();

  if (tid < 256) {
    const int k = tid >> 5, row = (tid >> 1) & 15, ch = tid & 1;
    const int boff = k * 256 + row * 16 + ch * 8;
    f32x4 s0 = {0.f, 0.f, 0.f, 0.f}, s1 = {0.f, 0.f, 0.f, 0.f};
    for (int ss = 0; ss < 8; ++ss) {
      s0 += *(const f32x4*)&pan[ss][boff];
      s1 += *(const f32x4*)&pan[ss][boff + 4];
    }
    const int b = b0 + row;
    if constexpr (G1) {
      const float* ca = A.c1Z + (((size_t)k * 64 + p * 2 + ch) * 64 + b) * 8;
      s0 += *(const f32x4*)ca;
      s1 += *(const f32x4*)(ca + 4);
    }
    float v[8];
#pragma unroll
    for (int e = 0; e < 4; ++e) { v[e] = s0[e]; v[4 + e] = s1[e]; }
    if (!fin) {
      u16x8 h8, l8;
#pragma unroll
      for (int e = 0; e < 8; ++e) {
        const u16 hh = bf_rnd(v[e]);
        h8[e] = hh;
        l8[e] = bf_rnd(v[e] - bf_val(hh));
      }
      const size_t zo =
          (((size_t)k * 96 + (G1 ? 32 : 0) + p * 2 + ch) * 64 + b) * 8;
      *(u16x8*)&A.Znh[zo] = h8;
      *(u16x8*)&A.Znl[zo] = l8;
    }
    if constexpr (G1) {
      if (t18) {
#pragma unroll
        for (int e = 0; e < 8; ++e)
          A.out1[((size_t)b * 512 + p * 16 + ch * 8 + e) * 8 + k] = v[e];
      }
    } else {
      if (fin) {
#pragma unroll
        for (int e = 0; e < 8; ++e)
          A.out2[((size_t)b * 256 + p * 16 + ch * 8 + e) * 8 + k] = v[e];
      }
    }
  }
}

__global__ __launch_bounds__(512) void iter_k(IArgs A, int t18, int fin) {
  __shared__ float pan[8][2048];
  if ((int)blockIdx.x < A.n_g1) iter_body<true>(A, t18, fin, pan);
  else iter_body<false>(A, t18, fin, pan);
}

extern "C" void kernel_launch(void* const* d_in, const int* in_sizes, int n_in,
                              void* d_out, int out_size, void* d_ws,
                              size_t ws_size, hipStream_t stream) {
  const float* x = (const float*)d_in[0];
  const float* w1 = (const float*)d_in[1];
  const float* w2 = (const float*)d_in[2];

  float* out0 = (float*)d_out;
  float* out1 = out0 + 131072;
  float* out2 = out1 + 262144;

  char* W = (char*)d_ws;
  const size_t MB = 1ull << 20;
  u16* Vpk1 = (u16*)(W);
  u16* Vpk2 = (u16*)(W + 8 * MB);
  u16* Q1 = (u16*)(W + 14 * MB);
  u16* Q2 = (u16*)(W + 18 * MB);
  u16* Qc1 = (u16*)(W + 22 * MB);
  u16* P1h = (u16*)(W + 26 * MB);
  u16* P1l = (u16*)(W + 28 * MB);
  u16* P2h = (u16*)(W + 30 * MB);
  u16* P2l = (u16*)(W + 32 * MB);
  u16* Axh = (u16*)(W + 34 * MB);
  u16* Axl = (u16*)(W + 34 * MB + 262144);
  float* c1Z = (float*)(W + 35 * MB);
  u16* Z0h = (u16*)(W + 46 * MB);
  u16* Z0l = Z0h + 393216;
  u16* Z1h = Z0h + 786432;
  u16* Z1l = Z0h + 1179648;

  // D1: pack raw inputs
  pack_in<<<2368, 256, 0, stream>>>(x, w1, w2, P1h, P1l, Q1, Qc1, P2h, P2l, Q2,
                                    Axh, Axl, Vpk2, Z0h, Z0l, out0);

  // D2: compose + fused operator pack
  composeK<<<1408, 512, 0, stream>>>(P1h, P1l, Q1, P2h, P2l, Q2, Axh, Axl, Qc1,
                                     Vpk1, Vpk2, Z0h, Z0l, c1Z);

  // D3..D21: 19 stream-ordered pair dispatches {g2_t, g1_{t+1}}
  for (int t = 0; t < 19; ++t) {
    IArgs ia;
    ia.Zch = (t & 1) ? Z1h : Z0h;
    ia.Zcl = (t & 1) ? Z1l : Z0l;
    ia.Znh = (t & 1) ? Z0h : Z1h;
    ia.Znl = (t & 1) ? Z0l : Z1l;
    ia.Vpk1 = Vpk1; ia.Vpk2 = Vpk2; ia.c1Z = c1Z;
    ia.out1 = out1; ia.out2 = nullptr;
    ia.n_g1 = 128;
    iter_k<<<192, 512, 0, stream>>>(ia, t == 18 ? 1 : 0, 0);
  }

  // D22: final g2_19 reads Z1 = [S2_19 | S1_20] -> out2 = S2_20
  {
    IArgs ia;
    ia.Zch = Z1h; ia.Zcl = Z1l;
    ia.Znh = Z0h; ia.Znl = Z0l;  // unused (fin)
    ia.Vpk1 = Vpk1; ia.Vpk2 = Vpk2; ia.c1Z = c1Z;
    ia.out1 = out1; ia.out2 = out2;
    ia.n_g1 = 0;
    iter_k<<<64, 512, 0, stream>>>(ia, 0, 1);
  }
}